// Round 6
// baseline (358.770 us; speedup 1.0000x reference)
//
#include <hip/hip_runtime.h>
#include <math.h>

#define HW 4096   // H*W = 64*64; B=4, C=64, H=W=64, L=4096

typedef short bf16x8 __attribute__((ext_vector_type(8)));
typedef float floatx4 __attribute__((ext_vector_type(4)));

__device__ __forceinline__ unsigned short f2bf_rne(float x) {
    unsigned int u = __float_as_uint(x);
    unsigned int r = (u + 0x7FFFu + ((u >> 16) & 1u)) >> 16;
    return (unsigned short)r;
}
__device__ __forceinline__ float bf2f(unsigned short h) {
    return __uint_as_float(((unsigned int)h) << 16);
}

// ---------------- prep: split fp32 -> bf16 (hi,lo), transpose to [p][c], ------
// fused per-pixel squared norms (pixnorm) since the data is already staged.
// Aq[b][p][0:64]=Qh, [64:128]=Qh, [128:192]=Ql   (A' = [Qh;Qh;Ql])
// Bq[b][p][0:64]=Kh, [64:128]=Kl, [128:192]=Kh   (B' = [Kh;Kl;Kh])
__global__ __launch_bounds__(256)
void prep_kernel(const float* __restrict__ Q, const float* __restrict__ K,
                 unsigned short* __restrict__ Aq, unsigned short* __restrict__ Bq,
                 float* __restrict__ pix2q, float* __restrict__ pix2k) {
    __shared__ float sT[64][65];
    const int tid = threadIdx.x;
    const int p0 = blockIdx.x * 64;
    const int b = blockIdx.y;
    const int pp = tid >> 2, qt = tid & 3;
    const size_t base = ((size_t)b * 4096 + p0 + pp) * 192;

    // ---- Q -> Aq + pix2q ----
#pragma unroll
    for (int it = 0; it < 16; ++it) {
        int idx = it * 256 + tid;
        int c = idx >> 6, x = idx & 63;
        sT[c][x] = Q[((size_t)b * 64 + c) * HW + p0 + x];
    }
    __syncthreads();
    {
        float sq = 0.f;
#pragma unroll
        for (int i = 0; i < 16; ++i) {
            int c = qt * 16 + i;
            float x = sT[c][pp];
            sq = fmaf(x, x, sq);
            unsigned short h = f2bf_rne(x);
            unsigned short l = f2bf_rne(x - bf2f(h));
            Aq[base + c] = h;
            Aq[base + 64 + c] = h;
            Aq[base + 128 + c] = l;
        }
        sq += __shfl_xor(sq, 1, 64);
        sq += __shfl_xor(sq, 2, 64);
        if (qt == 0) pix2q[(b << 12) + p0 + pp] = sq;
    }
    __syncthreads();

    // ---- K -> Bq + pix2k ----
#pragma unroll
    for (int it = 0; it < 16; ++it) {
        int idx = it * 256 + tid;
        int c = idx >> 6, x = idx & 63;
        sT[c][x] = K[((size_t)b * 64 + c) * HW + p0 + x];
    }
    __syncthreads();
    {
        float sk = 0.f;
#pragma unroll
        for (int i = 0; i < 16; ++i) {
            int c = qt * 16 + i;
            float x = sT[c][pp];
            sk = fmaf(x, x, sk);
            unsigned short h = f2bf_rne(x);
            unsigned short l = f2bf_rne(x - bf2f(h));
            Bq[base + c] = h;
            Bq[base + 64 + c] = l;
            Bq[base + 128 + c] = h;
        }
        sk += __shfl_xor(sk, 1, 64);
        sk += __shfl_xor(sk, 2, 64);
        if (qt == 0) pix2k[(b << 12) + p0 + pp] = sk;
    }
}

// ---------------- patch reciprocal norms: 1/max(sqrt(3x3 box sum), 1e-12) ----
__global__ void patchnorm_kernel(const float* __restrict__ pix2q, const float* __restrict__ pix2k,
                                 float* __restrict__ rnq, float* __restrict__ rnk) {
    int idx = blockIdx.x * 256 + threadIdx.x;   // b*4096 + p
    int b = idx >> 12, p = idx & 4095;
    int py = p >> 6, px = p & 63;
    float sq = 0.f, sk = 0.f;
    for (int dy = -1; dy <= 1; ++dy)
        for (int dx = -1; dx <= 1; ++dx) {
            int yy = py + dy, xx = px + dx;
            if ((unsigned)yy < 64u && (unsigned)xx < 64u) {
                int o = (b << 12) + (yy << 6) + xx;
                sq += pix2q[o];
                sk += pix2k[o];
            }
        }
    rnq[idx] = 1.f / fmaxf(sqrtf(sq), 1e-12f);
    rnk[idx] = 1.f / fmaxf(sqrtf(sk), 1e-12f);
}

// ---------------- MFMA GEMM (K=192 split-bf16) + fused x-diagonal 3-sum ------
// Dx[q][k] = D[q][k] + D[q-1][k-1]*(qx>0&kx>0) + D[q+1][k+1]*(qx<63&kx<63)
// Tile 128x128; 4 waves, each a 64x64 quadrant of 4x4 16x16x32 MFMAs.
// Single-batch Dx (64 MiB) so it stays cache-resident across gemm->reduce.
__global__ __launch_bounds__(256, 2)
void gemm_mfma_kernel(const unsigned short* __restrict__ Aq, const unsigned short* __restrict__ Bq,
                      float* __restrict__ Dx, int b) {
    __shared__ __align__(16) char smem[128 * 132 * 4];   // 67584 B >= 2*16384 staging
    const int tid = threadIdx.x;
    const int lane = tid & 63, wid = tid >> 6;
    const int m15 = lane & 15, quad = lane >> 4;
    const int wm = wid & 1, wn = wid >> 1;
    const int k0 = blockIdx.x * 128;
    const int q0 = blockIdx.y * 128;
    const unsigned short* Aqb = Aq + (size_t)b * 4096 * 192;
    const unsigned short* Bqb = Bq + (size_t)b * 4096 * 192;

    floatx4 acc[4][4];
#pragma unroll
    for (int i = 0; i < 4; ++i)
#pragma unroll
        for (int j = 0; j < 4; ++j) acc[i][j] = (floatx4)0.f;

    for (int s = 0; s < 3; ++s) {
        const int cbase = s * 64;
        // granule g of row r sits at position g^(r&7) -> frag reads 2-way aliased (free)
#pragma unroll
        for (int it = 0; it < 4; ++it) {
            int slot = it * 256 + tid;
            int row = slot >> 3, pos = slot & 7;
            int G = pos ^ (row & 7);
            uint4 va = *(const uint4*)(Aqb + ((size_t)(q0 + row)) * 192 + cbase + G * 8);
            uint4 vb = *(const uint4*)(Bqb + ((size_t)(k0 + row)) * 192 + cbase + G * 8);
            *(uint4*)(smem + slot * 16) = va;
            *(uint4*)(smem + 16384 + slot * 16) = vb;
        }
        __syncthreads();
#pragma unroll
        for (int kk = 0; kk < 2; ++kk) {
            bf16x8 af[4], bfr[4];
#pragma unroll
            for (int mt = 0; mt < 4; ++mt) {
                int row = wm * 64 + mt * 16 + m15;
                int pos = (kk * 4 + quad) ^ (row & 7);
                af[mt] = *(const bf16x8*)(smem + (row * 8 + pos) * 16);
            }
#pragma unroll
            for (int nt = 0; nt < 4; ++nt) {
                int row = wn * 64 + nt * 16 + m15;
                int pos = (kk * 4 + quad) ^ (row & 7);
                bfr[nt] = *(const bf16x8*)(smem + 16384 + (row * 8 + pos) * 16);
            }
#pragma unroll
            for (int mt = 0; mt < 4; ++mt)
#pragma unroll
                for (int nt = 0; nt < 4; ++nt)
                    acc[mt][nt] = __builtin_amdgcn_mfma_f32_16x16x32_bf16(
                        af[mt], bfr[nt], acc[mt][nt], 0, 0, 0);
        }
        __syncthreads();
    }

    // ---- epilogue: C tile -> LDS (stride 132), x-diag 3-sum, store Dx ----
    float* Csh = (float*)smem;
#pragma unroll
    for (int mt = 0; mt < 4; ++mt)
#pragma unroll
        for (int nt = 0; nt < 4; ++nt)
#pragma unroll
            for (int j = 0; j < 4; ++j)
                Csh[(wm * 64 + mt * 16 + quad * 4 + j) * 132 + wn * 64 + nt * 16 + m15] =
                    acc[mt][nt][j];
    __syncthreads();

    const int q_l = tid >> 1;
    const int cb = (tid & 1) * 64;
    const bool qm = (q_l & 63) > 0;      // diag- allowed in q (qx>0)
    const bool qp = (q_l & 63) < 63;     // diag+ allowed in q (qx<63)
    float4 prevm = make_float4(0.f, 0.f, 0.f, 0.f);
    float4 rpj   = qp ? *(const float4*)&Csh[(q_l + 1) * 132 + cb] : make_float4(0.f, 0.f, 0.f, 0.f);
    float* dst = Dx + (size_t)(q0 + q_l) * HW + k0 + cb;
#pragma unroll
    for (int j = 0; j < 16; ++j) {
        int c = cb + 4 * j;
        float4 cen = *(const float4*)&Csh[q_l * 132 + c];
        float4 rm  = qm ? *(const float4*)&Csh[(q_l - 1) * 132 + c] : make_float4(0.f, 0.f, 0.f, 0.f);
        float4 rp1 = (qp && j < 15) ? *(const float4*)&Csh[(q_l + 1) * 132 + c + 4]
                                    : make_float4(0.f, 0.f, 0.f, 0.f);
        float4 o;
        o.x = cen.x + prevm.w + rpj.y;
        o.y = cen.y + rm.x    + rpj.z;
        o.z = cen.z + rm.y    + rpj.w;
        o.w = cen.w + rm.z    + rp1.x;
        if (j == 0)  o.x = cen.x + rpj.y;   // kx==0: no diag-
        if (j == 15) o.w = cen.w + rm.z;    // kx==63: no diag+
        *(float4*)(dst + 4 * j) = o;
        prevm = rm;
        rpj = rp1;
    }
}

// ---------------- reduce: y-diagonal 3-sum + argmax, register pipeline, f2 ---
// R[(qy,qx)][(ky,kx)] = Dx[qy-1][ky-1] + Dx[qy][ky] + Dx[qy+1][ky+1] (same qx,kx)
// lane owns a kx-pair (float2), wave covers 2 qx; WG covers 8 qx x 64 kx.
__global__ __launch_bounds__(256, 4)
void reduce_kernel(const float* __restrict__ Dx, const float* __restrict__ rnkA,
                   float* __restrict__ part_val, int* __restrict__ part_arg, int b) {
    const int s = blockIdx.x;           // 0..7 ky split
    const int qxT = blockIdx.y;         // 0..7
    const int qyb = blockIdx.z;         // 0..7
    const int tid = threadIdx.x;
    const int lane = tid & 63, wv = tid >> 6;
    const int kx2 = (lane & 31) * 2;
    const int qxs = lane >> 5;
    const int qx = qxT * 8 + wv * 2 + qxs;
    const int qy0 = qyb * 8;

    float2 P0[8], P1[8], best[8];
    int barX[8], barY[8];
#pragma unroll
    for (int j = 0; j < 8; ++j) {
        P0[j] = make_float2(0.f, 0.f);
        P1[j] = make_float2(0.f, 0.f);
        best[j] = make_float2(-INFINITY, -INFINITY);
        barX[j] = 0; barY[j] = 0;
    }

    const int t0 = s * 8 - 1;
    for (int step = 0; step < 10; ++step) {
        int t = t0 + step;
        bool tval = (unsigned)t < 64u;
        float2 E[10];
#pragma unroll
        for (int lj = 0; lj < 10; ++lj) {
            int qy = qy0 - 1 + lj;
            bool v = tval && (unsigned)qy < 64u;
            E[lj] = v ? *(const float2*)&Dx[(size_t)((qy << 6) + qx) * HW + t * 64 + kx2]
                      : make_float2(0.f, 0.f);
        }
        if (step >= 2) {
            float2 rk = *(const float2*)&rnkA[(b << 12) + ((t - 1) << 6) + kx2];
            int kg = (t - 1) * 64 + kx2;
#pragma unroll
            for (int j = 0; j < 8; ++j) {
                float vx = (P1[j].x + E[j + 2].x) * rk.x;
                float vy = (P1[j].y + E[j + 2].y) * rk.y;
                if (vx > best[j].x) { best[j].x = vx; barX[j] = kg; }       // strict >
                if (vy > best[j].y) { best[j].y = vy; barY[j] = kg + 1; }
            }
        }
#pragma unroll
        for (int j = 0; j < 8; ++j) {
            P1[j].x = P0[j].x + E[j + 1].x;  P1[j].y = P0[j].y + E[j + 1].y;
            P0[j] = E[j];
        }
    }

#pragma unroll
    for (int j = 0; j < 8; ++j) {
        // merge slots: ties keep slot0 = lower k
        float v; int a;
        if (best[j].y > best[j].x) { v = best[j].y; a = barY[j]; }
        else                       { v = best[j].x; a = barX[j]; }
#pragma unroll
        for (int m = 16; m >= 1; m >>= 1) {   // reduce within 32-lane half (same qx)
            float ov = __shfl_xor(v, m, 64);
            int oa = __shfl_xor(a, m, 64);
            if (ov > v || (ov == v && oa < a)) { v = ov; a = oa; }
        }
        if ((lane & 31) == 0) {
            int qy = qy0 + j;
            int pi = ((b << 12) + (qy << 6) + qx) * 8 + s;
            part_val[pi] = v;
            part_arg[pi] = a;
        }
    }
}

// ---------------- gather + fold, fused combine -------------------------------
// Recomputes the 8-way s-combine for arg rows y-1..y+1 from partials (cheap),
// writes S for row y, then T[c,y,x] = (1/9) sum_{dy,dx} Vzp[c, a(q)+d], q=(y-dy,x-dx)
__global__ __launch_bounds__(256)
void gatherS_kernel(const float* __restrict__ V,
                    const float* __restrict__ part_val, const int* __restrict__ part_arg,
                    const float* __restrict__ rnqA,
                    float* __restrict__ S_out, float* __restrict__ T_out) {
    __shared__ int sArg[192];
    const int y = blockIdx.x, b = blockIdx.y;
    const int tid = threadIdx.x;
    if (tid < 192) {
        int r = tid >> 6, x = tid & 63;
        int yy = y - 1 + r;
        int a = 0;
        if ((unsigned)yy < 64u) {
            int idx = (b << 12) + (yy << 6) + x;
            const float* pv = part_val + (size_t)idx * 8;
            const int* pa = part_arg + (size_t)idx * 8;
            float bv = -INFINITY; int ba = 0;
#pragma unroll
            for (int s = 0; s < 8; ++s) {   // ascending s: first max wins
                float v = pv[s];
                int aa = pa[s];
                if (v > bv) { bv = v; ba = aa; }
            }
            a = ba;
            if (r == 1) S_out[idx] = bv * rnqA[idx];
        }
        sArg[tid] = a;
    }
    __syncthreads();

    const int x = tid & 63, cq = tid >> 6;
    int off[9];
#pragma unroll
    for (int t = 0; t < 9; ++t) {
        int dy = t / 3 - 1, dx = t % 3 - 1;
        int qy = y - dy, qx = x - dx;
        int o = -1;
        if ((unsigned)qy < 64u && (unsigned)qx < 64u) {
            int a = sArg[(1 - dy) * 64 + qx];
            int sy = (a >> 6) + dy, sx = (a & 63) + dx;
            if ((unsigned)sy < 64u && (unsigned)sx < 64u) o = (sy << 6) + sx;
        }
        off[t] = o;
    }
    const float* Vb = V + (size_t)b * 64 * HW;
    float* Tb = T_out + (size_t)b * 64 * HW + (y << 6) + x;
    for (int ci = 0; ci < 16; ++ci) {
        int c = cq * 16 + ci;
        const float* Vc = Vb + (size_t)c * HW;
        float acc = 0.f;
#pragma unroll
        for (int t = 0; t < 9; ++t)
            acc += (off[t] >= 0) ? Vc[off[t]] : 0.f;
        Tb[(size_t)c * HW] = acc * (1.f / 9.f);
    }
}

extern "C" void kernel_launch(void* const* d_in, const int* in_sizes, int n_in,
                              void* d_out, int out_size, void* d_ws, size_t ws_size,
                              hipStream_t stream) {
    const float* V = (const float*)d_in[0];
    const float* K = (const float*)d_in[1];
    const float* Q = (const float*)d_in[2];
    float* S_out = (float*)d_out;            // 4*4096
    float* T_out = S_out + 4 * HW;           // 4*64*4096

    char* ws = (char*)d_ws;
    float* pix2q = (float*)(ws + 0);                 // 64 KB
    float* pix2k = (float*)(ws + 65536);
    float* rnq   = (float*)(ws + 131072);
    float* rnk   = (float*)(ws + 196608);
    float* part_val = (float*)(ws + 262144);         // 512 KB
    int*   part_arg = (int*)(ws + 786432);           // 512 KB
    float* Dx = (float*)(ws + 1310720);              // single 64 MiB slab, reused per batch
    unsigned short* Aq = (unsigned short*)(ws + 68419584);    // 4*4096*192 bf16 = 6 MiB
    unsigned short* Bq = (unsigned short*)(ws + 74711040);    // 6 MiB

    prep_kernel<<<dim3(64, 4), 256, 0, stream>>>(Q, K, Aq, Bq, pix2q, pix2k);
    patchnorm_kernel<<<64, 256, 0, stream>>>(pix2q, pix2k, rnq, rnk);
    for (int b = 0; b < 4; ++b) {
        gemm_mfma_kernel<<<dim3(32, 32), 256, 0, stream>>>(Aq, Bq, Dx, b);
        reduce_kernel<<<dim3(8, 8, 8), 256, 0, stream>>>(Dx, rnk, part_val, part_arg, b);
    }
    gatherS_kernel<<<dim3(64, 4), 256, 0, stream>>>(V, part_val, part_arg, rnq, S_out, T_out);
}

// Round 7
// 262.320 us; speedup vs baseline: 1.3677x; 1.3677x over previous
//
#include <hip/hip_runtime.h>
#include <math.h>

#define HW 4096   // H*W = 64*64; B=4, C=64, H=W=64, L=4096

typedef short bf16x8 __attribute__((ext_vector_type(8)));
typedef float floatx4 __attribute__((ext_vector_type(4)));

__device__ __forceinline__ unsigned short f2bf_rne(float x) {
    unsigned int u = __float_as_uint(x);
    unsigned int r = (u + 0x7FFFu + ((u >> 16) & 1u)) >> 16;
    return (unsigned short)r;
}
__device__ __forceinline__ float bf2f(unsigned short h) {
    return __uint_as_float(((unsigned int)h) << 16);
}

// ---------------- prep: split fp32 -> bf16 (hi,lo), transpose to [p][c], ------
// fused per-pixel squared norms. Aq[b][p] = [Qh|Qh|Ql], Bq[b][p] = [Kh|Kl|Kh]
// so a 192-dot gives QhKh + QhKl + QlKh ~= fp32 dot.
__global__ __launch_bounds__(256)
void prep_kernel(const float* __restrict__ Q, const float* __restrict__ K,
                 unsigned short* __restrict__ Aq, unsigned short* __restrict__ Bq,
                 float* __restrict__ pix2q, float* __restrict__ pix2k) {
    __shared__ float sT[64][65];
    const int tid = threadIdx.x;
    const int p0 = blockIdx.x * 64;
    const int b = blockIdx.y;
    const int pp = tid >> 2, qt = tid & 3;
    const size_t base = ((size_t)b * 4096 + p0 + pp) * 192;

#pragma unroll
    for (int it = 0; it < 16; ++it) {
        int idx = it * 256 + tid;
        int c = idx >> 6, x = idx & 63;
        sT[c][x] = Q[((size_t)b * 64 + c) * HW + p0 + x];
    }
    __syncthreads();
    {
        float sq = 0.f;
#pragma unroll
        for (int i = 0; i < 16; ++i) {
            int c = qt * 16 + i;
            float x = sT[c][pp];
            sq = fmaf(x, x, sq);
            unsigned short h = f2bf_rne(x);
            unsigned short l = f2bf_rne(x - bf2f(h));
            Aq[base + c] = h;
            Aq[base + 64 + c] = h;
            Aq[base + 128 + c] = l;
        }
        sq += __shfl_xor(sq, 1, 64);
        sq += __shfl_xor(sq, 2, 64);
        if (qt == 0) pix2q[(b << 12) + p0 + pp] = sq;
    }
    __syncthreads();

#pragma unroll
    for (int it = 0; it < 16; ++it) {
        int idx = it * 256 + tid;
        int c = idx >> 6, x = idx & 63;
        sT[c][x] = K[((size_t)b * 64 + c) * HW + p0 + x];
    }
    __syncthreads();
    {
        float sk = 0.f;
#pragma unroll
        for (int i = 0; i < 16; ++i) {
            int c = qt * 16 + i;
            float x = sT[c][pp];
            sk = fmaf(x, x, sk);
            unsigned short h = f2bf_rne(x);
            unsigned short l = f2bf_rne(x - bf2f(h));
            Bq[base + c] = h;
            Bq[base + 64 + c] = l;
            Bq[base + 128 + c] = h;
        }
        sk += __shfl_xor(sk, 1, 64);
        sk += __shfl_xor(sk, 2, 64);
        if (qt == 0) pix2k[(b << 12) + p0 + pp] = sk;
    }
}

// ---------------- patch reciprocal norms: 1/max(sqrt(3x3 box sum), 1e-12) ----
__global__ void patchnorm_kernel(const float* __restrict__ pix2q, const float* __restrict__ pix2k,
                                 float* __restrict__ rnq, float* __restrict__ rnk) {
    int idx = blockIdx.x * 256 + threadIdx.x;   // b*4096 + p
    int b = idx >> 12, p = idx & 4095;
    int py = p >> 6, px = p & 63;
    float sq = 0.f, sk = 0.f;
    for (int dy = -1; dy <= 1; ++dy)
        for (int dx = -1; dx <= 1; ++dx) {
            int yy = py + dy, xx = px + dx;
            if ((unsigned)yy < 64u && (unsigned)xx < 64u) {
                int o = (b << 12) + (yy << 6) + xx;
                sq += pix2q[o];
                sk += pix2k[o];
            }
        }
    rnq[idx] = 1.f / fmaxf(sqrtf(sq), 1e-12f);
    rnk[idx] = 1.f / fmaxf(sqrtf(sk), 1e-12f);
}

// ---------------- fused MFMA GEMM (K=576: y-3sum in K) + x-3sum + argmax -----
// Stage s = (dy = s/3, seg = s%3): A rows offset by (dy-1)*64 (zero at qy edges),
// B rows offset by (dy-1)*64 (zero at ky edges). Sum over 576 = y-diagonal 3-sum
// of D. Epilogue: x-diagonal 3-sum (tile-local, edge-masked) -> R tile, then
// per-q max/argmax over the 128-k tile * rnk, one partial per (q, ktile).
// No D intermediate ever touches memory.
__global__ __launch_bounds__(256, 2)
void gemm_fused_kernel(const unsigned short* __restrict__ Aq, const unsigned short* __restrict__ Bq,
                       const float* __restrict__ rnkA,
                       float* __restrict__ part_val, int* __restrict__ part_arg) {
    __shared__ __align__(16) char smem[128 * 132 * 4];   // staging 2x16KB; epilogue Csh[128][132]
    const int tid = threadIdx.x;
    const int lane = tid & 63, wid = tid >> 6;
    const int m15 = lane & 15, quad = lane >> 4;
    const int wm = wid & 1, wn = wid >> 1;
    const int k0 = blockIdx.x * 128;
    const int q0 = blockIdx.y * 128;
    const int b = blockIdx.z;
    const unsigned short* Aqb = Aq + (size_t)b * 4096 * 192;
    const unsigned short* Bqb = Bq + (size_t)b * 4096 * 192;

    floatx4 acc[4][4];
#pragma unroll
    for (int i = 0; i < 4; ++i)
#pragma unroll
        for (int j = 0; j < 4; ++j) acc[i][j] = (floatx4)0.f;

    for (int s = 0; s < 9; ++s) {
        const int dy = s / 3;              // 0,1,2
        const int seg = s - dy * 3;        // 0,1,2
        const int rofs = (dy - 1) * 64;    // y-shift in pixel index
        // granule g of local row r at position g^(r&7) -> frag reads 2-way aliased (free)
#pragma unroll
        for (int it = 0; it < 4; ++it) {
            int slot = it * 256 + tid;
            int row = slot >> 3, pos = slot & 7;
            int G = pos ^ (row & 7);
            int ra = q0 + row + rofs;      // q + (dy-1)*64 : qy+-1, zero outside image
            int rb = k0 + row + rofs;      // k + (dy-1)*64 : ky+-1, zero outside image
            uint4 va = make_uint4(0u, 0u, 0u, 0u), vb = make_uint4(0u, 0u, 0u, 0u);
            if ((unsigned)ra < 4096u)
                va = *(const uint4*)(Aqb + (size_t)ra * 192 + seg * 64 + G * 8);
            if ((unsigned)rb < 4096u)
                vb = *(const uint4*)(Bqb + (size_t)rb * 192 + seg * 64 + G * 8);
            *(uint4*)(smem + slot * 16) = va;
            *(uint4*)(smem + 16384 + slot * 16) = vb;
        }
        __syncthreads();
#pragma unroll
        for (int kk = 0; kk < 2; ++kk) {
            bf16x8 af[4], bfr[4];
#pragma unroll
            for (int mt = 0; mt < 4; ++mt) {
                int row = wm * 64 + mt * 16 + m15;
                int pos = (kk * 4 + quad) ^ (row & 7);
                af[mt] = *(const bf16x8*)(smem + (row * 8 + pos) * 16);
            }
#pragma unroll
            for (int nt = 0; nt < 4; ++nt) {
                int row = wn * 64 + nt * 16 + m15;
                int pos = (kk * 4 + quad) ^ (row & 7);
                bfr[nt] = *(const bf16x8*)(smem + 16384 + (row * 8 + pos) * 16);
            }
#pragma unroll
            for (int mt = 0; mt < 4; ++mt)
#pragma unroll
                for (int nt = 0; nt < 4; ++nt)
                    acc[mt][nt] = __builtin_amdgcn_mfma_f32_16x16x32_bf16(
                        af[mt], bfr[nt], acc[mt][nt], 0, 0, 0);
        }
        __syncthreads();
    }

    // ---- epilogue: Dy tile -> LDS, x-diag 3-sum -> R, max/argmax over k ----
    float* Csh = (float*)smem;
#pragma unroll
    for (int mt = 0; mt < 4; ++mt)
#pragma unroll
        for (int nt = 0; nt < 4; ++nt)
#pragma unroll
            for (int j = 0; j < 4; ++j)
                Csh[(wm * 64 + mt * 16 + quad * 4 + j) * 132 + wn * 64 + nt * 16 + m15] =
                    acc[mt][nt][j];
    __syncthreads();

    const int q_l = tid >> 1;            // 0..127
    const int cb = (tid & 1) * 64;       // k-half within the 128 tile
    const bool qm = (q_l & 63) > 0;      // qx>0: diag- allowed
    const bool qp = (q_l & 63) < 63;     // qx<63: diag+ allowed
    float4 prevm = make_float4(0.f, 0.f, 0.f, 0.f);
    float4 rpj   = qp ? *(const float4*)&Csh[(q_l + 1) * 132 + cb] : make_float4(0.f, 0.f, 0.f, 0.f);
    float bv = -INFINITY;
    int ba = 0;
#pragma unroll
    for (int j = 0; j < 16; ++j) {
        int c = cb + 4 * j;
        float4 cen = *(const float4*)&Csh[q_l * 132 + c];
        float4 rm  = qm ? *(const float4*)&Csh[(q_l - 1) * 132 + c] : make_float4(0.f, 0.f, 0.f, 0.f);
        float4 rp1 = (qp && j < 15) ? *(const float4*)&Csh[(q_l + 1) * 132 + c + 4]
                                    : make_float4(0.f, 0.f, 0.f, 0.f);
        float4 o;
        o.x = cen.x + prevm.w + rpj.y;
        o.y = cen.y + rm.x    + rpj.z;
        o.z = cen.z + rm.y    + rpj.w;
        o.w = cen.w + rm.z    + rp1.x;
        if (j == 0)  o.x = cen.x + rpj.y;   // kx==0: no diag-
        if (j == 15) o.w = cen.w + rm.z;    // kx==63: no diag+
        float4 rk = *(const float4*)&rnkA[(b << 12) + k0 + c];
        // ascending k + strict > = first-occurrence argmax
        float vx = o.x * rk.x; if (vx > bv) { bv = vx; ba = k0 + c + 0; }
        float vy = o.y * rk.y; if (vy > bv) { bv = vy; ba = k0 + c + 1; }
        float vz = o.z * rk.z; if (vz > bv) { bv = vz; ba = k0 + c + 2; }
        float vw = o.w * rk.w; if (vw > bv) { bv = vw; ba = k0 + c + 3; }
        prevm = rm;
        rpj = rp1;
    }
    // merge the two k-halves (adjacent lanes); lower k wins ties
    {
        float ov = __shfl_xor(bv, 1, 64);
        int oa = __shfl_xor(ba, 1, 64);
        if (ov > bv || (ov == bv && oa < ba)) { bv = ov; ba = oa; }
    }
    if ((tid & 1) == 0) {
        int pi = ((b << 12) + q0 + q_l) * 32 + blockIdx.x;
        part_val[pi] = bv;
        part_arg[pi] = ba;
    }
}

// ---------------- gather + fold, fused combine (32 k-tile partials) ----------
// Combines partials for arg rows y-1..y+1, writes S for row y, then
// T[c,y,x] = (1/9) sum_{dy,dx} Vzp[c, a(q)+d], q=(y-dy,x-dx)
__global__ __launch_bounds__(256)
void gatherS_kernel(const float* __restrict__ V,
                    const float* __restrict__ part_val, const int* __restrict__ part_arg,
                    const float* __restrict__ rnqA,
                    float* __restrict__ S_out, float* __restrict__ T_out) {
    __shared__ int sArg[192];
    const int y = blockIdx.x, b = blockIdx.y;
    const int tid = threadIdx.x;
    if (tid < 192) {
        int r = tid >> 6, x = tid & 63;
        int yy = y - 1 + r;
        int a = 0;
        if ((unsigned)yy < 64u) {
            int idx = (b << 12) + (yy << 6) + x;
            const float* pv = part_val + (size_t)idx * 32;
            const int* pa = part_arg + (size_t)idx * 32;
            float bv = -INFINITY; int ba = 0;
#pragma unroll 8
            for (int s = 0; s < 32; ++s) {   // ascending ktile: first max wins
                float v = pv[s];
                int aa = pa[s];
                if (v > bv) { bv = v; ba = aa; }
            }
            a = ba;
            if (r == 1) S_out[idx] = bv * rnqA[idx];
        }
        sArg[tid] = a;
    }
    __syncthreads();

    const int x = tid & 63, cq = tid >> 6;
    int off[9];
#pragma unroll
    for (int t = 0; t < 9; ++t) {
        int dy = t / 3 - 1, dx = t % 3 - 1;
        int qy = y - dy, qx = x - dx;
        int o = -1;
        if ((unsigned)qy < 64u && (unsigned)qx < 64u) {
            int a = sArg[(1 - dy) * 64 + qx];
            int sy = (a >> 6) + dy, sx = (a & 63) + dx;
            if ((unsigned)sy < 64u && (unsigned)sx < 64u) o = (sy << 6) + sx;
        }
        off[t] = o;
    }
    const float* Vb = V + (size_t)b * 64 * HW;
    float* Tb = T_out + (size_t)b * 64 * HW + (y << 6) + x;
    for (int ci = 0; ci < 16; ++ci) {
        int c = cq * 16 + ci;
        const float* Vc = Vb + (size_t)c * HW;
        float acc = 0.f;
#pragma unroll
        for (int t = 0; t < 9; ++t)
            acc += (off[t] >= 0) ? Vc[off[t]] : 0.f;
        Tb[(size_t)c * HW] = acc * (1.f / 9.f);
    }
}

extern "C" void kernel_launch(void* const* d_in, const int* in_sizes, int n_in,
                              void* d_out, int out_size, void* d_ws, size_t ws_size,
                              hipStream_t stream) {
    const float* V = (const float*)d_in[0];
    const float* K = (const float*)d_in[1];
    const float* Q = (const float*)d_in[2];
    float* S_out = (float*)d_out;            // 4*4096
    float* T_out = S_out + 4 * HW;           // 4*64*4096

    char* ws = (char*)d_ws;
    float* pix2q = (float*)(ws + 0);                 // 64 KB
    float* pix2k = (float*)(ws + 65536);
    float* rnq   = (float*)(ws + 131072);
    float* rnk   = (float*)(ws + 196608);
    float* part_val = (float*)(ws + 262144);         // 4*4096*32 f = 2 MB
    int*   part_arg = (int*)(ws + 2359296);          // 2 MB
    unsigned short* Aq = (unsigned short*)(ws + 4456448);    // 4*4096*192 bf16 = 6 MiB
    unsigned short* Bq = (unsigned short*)(ws + 10747904);   // 6 MiB

    prep_kernel<<<dim3(64, 4), 256, 0, stream>>>(Q, K, Aq, Bq, pix2q, pix2k);
    patchnorm_kernel<<<64, 256, 0, stream>>>(pix2q, pix2k, rnq, rnk);
    gemm_fused_kernel<<<dim3(32, 32, 4), 256, 0, stream>>>(Aq, Bq, rnk, part_val, part_arg);
    gatherS_kernel<<<dim3(64, 4), 256, 0, stream>>>(V, part_val, part_arg, rnq, S_out, T_out);
}